// Round 6
// baseline (427.463 us; speedup 1.0000x reference)
//
#include <hip/hip_runtime.h>

// Double bilinear grid_sample (align_corners=False, zeros padding), fused.
// feature: [8,64,256,256] f32 NCHW; grid: [8,256,256,2] f32.
//
// K1: transpose feature NCHW -> grouped NHWC16: [n][4][65536 px][16 ch].
//     256hw x 64c tiles, 1 KB contiguous nt reads, XOR-swizzled LDS,
//     16 KB contiguous nt writes (fg is consumed on a different XCD).
// K2: fused double-sample, channel-split for L2 residency (r3: FETCH
//     797->232 MB, 245->170 us). Phase 2 = r3's exact structure (r4's
//     float4 lanes and r5's b128-desc/2-pt-unroll BOTH regressed: the
//     TA serializes intra-instruction segments, and restructuring the
//     inner loop broke the scheduler's latency hiding; 4x64B segments
//     per instr + 16-deep load runs is the local optimum).
//     r6: one launch PER GROUP (g as kernel arg) instead of gridDim.y=4:
//     (a) instrumentation -- gs dispatches drop to ~42 us so the
//     transpose must surface in rocprof top-5 with its counters;
//     (b) strictly one 4 MB slice live per XCD at a time.
//     Per-(point,channel) fma order unchanged -> bit-identical output.

#define GS_N 8
#define GS_C 64
#define GS_H 256
#define GS_W 256
#define GS_HW (GS_H * GS_W)
#define GS_IMG (GS_C * GS_HW)
#define GS_G 4                 // channel groups
#define GS_GC 16               // channels per group

typedef float f4v __attribute__((ext_vector_type(4)));

__global__ __launch_bounds__(256) void transpose_nchw_to_g16(
        const float* __restrict__ src, float* __restrict__ dst) {
    int b   = blockIdx.x;               // 2048 blocks: 256 hw x 64 c tile
    int n   = b >> 8;
    int hw0 = (b & 255) << 8;

    // Flat 64 KiB: row c = floats [c*256, c*256+256) as 64 float4 slots;
    // logical slot s of row c lives at phys slot s ^ (c>>3).
    __shared__ float lt[GS_C * 256];

    const float* sp = src + (size_t)n * GS_IMG + hw0;

    int l  = threadIdx.x & 63;
    int wv = threadIdx.x >> 6;

    // ---- Phase A: wave = one channel per instruction; 1 KB contiguous
    // nt read (feature is dead after this kernel).
    #pragma unroll
    for (int t = 0; t < 16; ++t) {
        int c = (wv << 4) + t;
        f4v v = __builtin_nontemporal_load(
                    (const f4v*)(sp + ((size_t)c << 16) + (l << 2)));
        int s = l ^ (c >> 3);           // swizzled float4 slot
        *(f4v*)&lt[(c << 8) + (s << 2)] = v;
    }
    __syncthreads();

    // ---- Phase B: write grouped NHWC16. c4 = float4 group of channels
    // [4*c4, 4*c4+4) = group g = c4>>2, in-row float offset (c4&3)*4.
    int c4  = threadIdx.x & 15;
    int h0  = threadIdx.x >> 4;
    int g   = c4 >> 2;
    int cl0 = (c4 & 3) << 2;
    int swz = c4 >> 1;                  // == (4*c4+k)>>3 for k=0..3
    int c0  = c4 << 2;
    float* dp = dst + ((size_t)(n * GS_G + g) << 20)   // 4 MB slice
              + ((size_t)hw0 << 4) + cl0;
    #pragma unroll
    for (int t = 0; t < 16; ++t) {
        int hh  = h0 + (t << 4);
        int col = (((hh >> 2) ^ swz) << 2) | (hh & 3);  // float idx in row
        f4v v;
        v.x = lt[((c0 + 0) << 8) + col];
        v.y = lt[((c0 + 1) << 8) + col];
        v.z = lt[((c0 + 2) << 8) + col];
        v.w = lt[((c0 + 3) << 8) + col];
        __builtin_nontemporal_store(v, (f4v*)(dp + ((size_t)hh << 4)));
    }
}

__device__ __forceinline__ void corner_setup(float gx, float gy,
        int& x0, int& y0, float& w00, float& w01, float& w10, float& w11) {
    // ix = ((gx+1)*256 - 1)*0.5 = gx*128 + 127.5
    float ix = fmaf(gx, 128.0f, 127.5f);
    float iy = fmaf(gy, 128.0f, 127.5f);
    float fx0 = floorf(ix), fy0 = floorf(iy);
    float fx = ix - fx0, fy = iy - fy0;
    x0 = (int)fx0; y0 = (int)fy0;
    int x1 = x0 + 1, y1 = y0 + 1;
    float mx0 = (x0 >= 0 && x0 < GS_W) ? 1.0f : 0.0f;
    float mx1 = (x1 >= 0 && x1 < GS_W) ? 1.0f : 0.0f;
    float my0 = (y0 >= 0 && y0 < GS_H) ? 1.0f : 0.0f;
    float my1 = (y1 >= 0 && y1 < GS_H) ? 1.0f : 0.0f;
    w00 = (1.0f - fx) * (1.0f - fy) * mx0 * my0;
    w01 = fx * (1.0f - fy) * mx1 * my0;
    w10 = (1.0f - fx) * fy * mx0 * my1;
    w11 = fx * fy * mx1 * my1;
}

__global__ __launch_bounds__(256) void gs_fused(
        const float* __restrict__ fg, const float* __restrict__ grid,
        float* __restrict__ out, int g) {
    int bx  = blockIdx.x;              // 8192
    int n   = bx & 7;                  // XCD pin: HW round-robin, XCD = bx%8
    int idx = bx >> 3;                 // 0..1023
    int p0  = (n << 16) + (idx << 6);  // first point (n,ho,wo0)

    __shared__ int2  s_desc[64][17];   // [point][entry] {byte_off, weight}
    __shared__ float tile[GS_GC][65];  // [ch-in-group][point]

    const float2* g2 = (const float2*)grid + (size_t)n * (size_t)GS_HW;

    // ---- Phase 1: all 256 threads; thread = (point, corner k).
    {
        int pt = threadIdx.x >> 2;
        int k  = threadIdx.x & 3;
        float2 gp = ((const float2*)grid)[p0 + pt];   // 4-thread broadcast
        int ox0, oy0; float w00, w01, w10, w11;
        corner_setup(gp.x, gp.y, ox0, oy0, w00, w01, w10, w11);
        int x0c = min(max(ox0, 0), GS_W - 1), x1c = min(max(ox0 + 1, 0), GS_W - 1);
        int y0c = min(max(oy0, 0), GS_H - 1), y1c = min(max(oy0 + 1, 0), GS_H - 1);
        int   qx = (k & 1) ? x1c : x0c;               // k order matches r3:
        int   qy = (k >> 1) ? y1c : y0c;              // 00,01,10,11
        float wk = (k == 0) ? w00 : (k == 1) ? w01 : (k == 2) ? w10 : w11;
        float2 gi = g2[qy * GS_W + qx];               // 8 B gather, L2-resident
        int ix0, iy0; float u00, u01, u10, u11;
        corner_setup(gi.x, gi.y, ix0, iy0, u00, u01, u10, u11);
        int a0 = min(max(ix0, 0), GS_W - 1), a1 = min(max(ix0 + 1, 0), GS_W - 1);
        int b0 = min(max(iy0, 0), GS_H - 1), b1 = min(max(iy0 + 1, 0), GS_H - 1);
        // byte offset of the 64 B group row: pixel * 16 ch * 4 B
        s_desc[pt][k * 4 + 0] = make_int2((b0 * GS_W + a0) << 6, __float_as_int(wk * u00));
        s_desc[pt][k * 4 + 1] = make_int2((b0 * GS_W + a1) << 6, __float_as_int(wk * u01));
        s_desc[pt][k * 4 + 2] = make_int2((b1 * GS_W + a0) << 6, __float_as_int(wk * u10));
        s_desc[pt][k * 4 + 3] = make_int2((b1 * GS_W + a1) << 6, __float_as_int(wk * u11));
    }
    __syncthreads();

    // ---- Phase 2: lane = (pt-oct, channel); 16 points per wave.
    {
        int lane = threadIdx.x & 63;
        int wave = threadIdx.x >> 6;
        int ch4  = (lane & 15) << 2;   // byte offset of channel in row
        int ps   = lane >> 4;          // 0..3: point within quartet
        const char* fbc = (const char*)(fg + ((size_t)(n * GS_G + g) << 20));
        #pragma unroll 1
        for (int s = 0; s < 4; ++s) {
            int sl = wave * 16 + s * 4 + ps;
            float acc = 0.0f;
            #pragma unroll
            for (int e = 0; e < 16; ++e) {
                int2 d = s_desc[sl][e];                   // 16-lane broadcast
                float v = *(const float*)(fbc + (size_t)(d.x + ch4));  // 64 B/pt
                acc = fmaf(__int_as_float(d.y), v, acc);
            }
            tile[lane & 15][sl] = acc;
        }
    }
    __syncthreads();

    // ---- coalesced NCHW write, non-temporal (don't pollute L2 slice)
    int ho  = (p0 >> 8) & 255;
    int wo0 = p0 & 255;
    float* ob = out + (size_t)n * GS_IMG + ((size_t)(g * GS_GC) << 16)
              + (size_t)ho * GS_W + wo0;
    int w  = threadIdx.x & 63;
    int c0 = threadIdx.x >> 6;
    #pragma unroll
    for (int c = c0; c < GS_GC; c += 4)
        __builtin_nontemporal_store(tile[c][w], ob + ((size_t)c << 16) + w);
}

extern "C" void kernel_launch(void* const* d_in, const int* in_sizes, int n_in,
                              void* d_out, int out_size, void* d_ws, size_t ws_size,
                              hipStream_t stream) {
    const float* feature = (const float*)d_in[0];
    const float* grid    = (const float*)d_in[1];
    float*       out     = (float*)d_out;
    float*       fg      = (float*)d_ws;           // 128 MiB grouped-NHWC16

    dim3 block(256);

    transpose_nchw_to_g16<<<dim3(GS_N * GS_HW / 256), block, 0, stream>>>(feature, fg);
    for (int g = 0; g < GS_G; ++g)
        gs_fused<<<dim3(GS_N * GS_HW / 64), block, 0, stream>>>(fg, grid, out, g);
}

// Round 7
// 418.308 us; speedup vs baseline: 1.0219x; 1.0219x over previous
//
#include <hip/hip_runtime.h>

// Double bilinear grid_sample (align_corners=False, zeros padding), fused.
// feature: [8,64,256,256] f32 NCHW; grid: [8,256,256,2] f32.
//
// Budget (r6 discovery): measured window includes the harness's 512 MiB
// workspace re-poison fill (~79 us @6.8 TB/s, immovable) + transpose
// (<78 us, near roofline) + gs_fused (the only attackable term).
//
// K1: transpose feature NCHW -> grouped NHWC16: [n][4][65536 px][16 ch].
//     256hw x 64c tiles, 1 KB contiguous nt reads, XOR-swizzled LDS,
//     16 KB contiguous nt writes.
// K2: fused double-sample, channel-split for L2 residency (r3: FETCH
//     797->232 MB, 245->170 us). Inner loop = r3 EXACT (r4 float4-lane
//     and r5 b128-desc/unroll both regressed -- do not restructure).
//     r7: single launch again (r6's 4-way split cost +50 us in drains)
//     and 512-thread blocks (128 pts, 8 waves): 4 WG/CU fills all 32
//     wave slots (r3: 256-thr needed 8 WG/CU, occupancy stuck at 68%),
//     halves barrier/epilogue overhead. Per-(pt,ch) fma order unchanged
//     -> bit-identical output.

#define GS_N 8
#define GS_C 64
#define GS_H 256
#define GS_W 256
#define GS_HW (GS_H * GS_W)
#define GS_IMG (GS_C * GS_HW)
#define GS_G 4                 // channel groups
#define GS_GC 16               // channels per group
#define GS_PTS 128             // points per gs block

typedef float f4v __attribute__((ext_vector_type(4)));

__global__ __launch_bounds__(256) void transpose_nchw_to_g16(
        const float* __restrict__ src, float* __restrict__ dst) {
    int b   = blockIdx.x;               // 2048 blocks: 256 hw x 64 c tile
    int n   = b >> 8;
    int hw0 = (b & 255) << 8;

    // Flat 64 KiB: row c = floats [c*256, c*256+256) as 64 float4 slots;
    // logical slot s of row c lives at phys slot s ^ (c>>3).
    __shared__ float lt[GS_C * 256];

    const float* sp = src + (size_t)n * GS_IMG + hw0;

    int l  = threadIdx.x & 63;
    int wv = threadIdx.x >> 6;

    // ---- Phase A: wave = one channel per instruction; 1 KB contiguous
    // nt read (feature is dead after this kernel).
    #pragma unroll
    for (int t = 0; t < 16; ++t) {
        int c = (wv << 4) + t;
        f4v v = __builtin_nontemporal_load(
                    (const f4v*)(sp + ((size_t)c << 16) + (l << 2)));
        int s = l ^ (c >> 3);           // swizzled float4 slot
        *(f4v*)&lt[(c << 8) + (s << 2)] = v;
    }
    __syncthreads();

    // ---- Phase B: write grouped NHWC16. c4 = float4 group of channels
    // [4*c4, 4*c4+4) = group g = c4>>2, in-row float offset (c4&3)*4.
    int c4  = threadIdx.x & 15;
    int h0  = threadIdx.x >> 4;
    int g   = c4 >> 2;
    int cl0 = (c4 & 3) << 2;
    int swz = c4 >> 1;                  // == (4*c4+k)>>3 for k=0..3
    int c0  = c4 << 2;
    float* dp = dst + ((size_t)(n * GS_G + g) << 20)   // 4 MB slice
              + ((size_t)hw0 << 4) + cl0;
    #pragma unroll
    for (int t = 0; t < 16; ++t) {
        int hh  = h0 + (t << 4);
        int col = (((hh >> 2) ^ swz) << 2) | (hh & 3);  // float idx in row
        f4v v;
        v.x = lt[((c0 + 0) << 8) + col];
        v.y = lt[((c0 + 1) << 8) + col];
        v.z = lt[((c0 + 2) << 8) + col];
        v.w = lt[((c0 + 3) << 8) + col];
        __builtin_nontemporal_store(v, (f4v*)(dp + ((size_t)hh << 4)));
    }
}

__device__ __forceinline__ void corner_setup(float gx, float gy,
        int& x0, int& y0, float& w00, float& w01, float& w10, float& w11) {
    // ix = ((gx+1)*256 - 1)*0.5 = gx*128 + 127.5
    float ix = fmaf(gx, 128.0f, 127.5f);
    float iy = fmaf(gy, 128.0f, 127.5f);
    float fx0 = floorf(ix), fy0 = floorf(iy);
    float fx = ix - fx0, fy = iy - fy0;
    x0 = (int)fx0; y0 = (int)fy0;
    int x1 = x0 + 1, y1 = y0 + 1;
    float mx0 = (x0 >= 0 && x0 < GS_W) ? 1.0f : 0.0f;
    float mx1 = (x1 >= 0 && x1 < GS_W) ? 1.0f : 0.0f;
    float my0 = (y0 >= 0 && y0 < GS_H) ? 1.0f : 0.0f;
    float my1 = (y1 >= 0 && y1 < GS_H) ? 1.0f : 0.0f;
    w00 = (1.0f - fx) * (1.0f - fy) * mx0 * my0;
    w01 = fx * (1.0f - fy) * mx1 * my0;
    w10 = (1.0f - fx) * fy * mx0 * my1;
    w11 = fx * fy * mx1 * my1;
}

__global__ __launch_bounds__(512) void gs_fused(
        const float* __restrict__ fg, const float* __restrict__ grid,
        float* __restrict__ out) {
    int bx  = blockIdx.x;              // 4096
    int g   = blockIdx.y;              // channel group (x-fastest dispatch)
    int n   = bx & 7;                  // XCD pin: 4096%8==0, XCD = bx%8
    int idx = bx >> 3;                 // 0..511
    int p0  = (n << 16) + (idx << 7);  // first point (n,ho,wo0)

    __shared__ int2  s_desc[GS_PTS][17];   // [point][entry] {byte_off, w}
    __shared__ float tile[GS_GC][130];     // [ch-in-group][point]

    const float2* g2 = (const float2*)grid + (size_t)n * (size_t)GS_HW;

    // ---- Phase 1: all 512 threads; thread = (point, corner k).
    {
        int pt = threadIdx.x >> 2;
        int k  = threadIdx.x & 3;
        float2 gp = ((const float2*)grid)[p0 + pt];   // 4-thread broadcast
        int ox0, oy0; float w00, w01, w10, w11;
        corner_setup(gp.x, gp.y, ox0, oy0, w00, w01, w10, w11);
        int x0c = min(max(ox0, 0), GS_W - 1), x1c = min(max(ox0 + 1, 0), GS_W - 1);
        int y0c = min(max(oy0, 0), GS_H - 1), y1c = min(max(oy0 + 1, 0), GS_H - 1);
        int   qx = (k & 1) ? x1c : x0c;               // k order matches r3:
        int   qy = (k >> 1) ? y1c : y0c;              // 00,01,10,11
        float wk = (k == 0) ? w00 : (k == 1) ? w01 : (k == 2) ? w10 : w11;
        float2 gi = g2[qy * GS_W + qx];               // 8 B gather, L2-resident
        int ix0, iy0; float u00, u01, u10, u11;
        corner_setup(gi.x, gi.y, ix0, iy0, u00, u01, u10, u11);
        int a0 = min(max(ix0, 0), GS_W - 1), a1 = min(max(ix0 + 1, 0), GS_W - 1);
        int b0 = min(max(iy0, 0), GS_H - 1), b1 = min(max(iy0 + 1, 0), GS_H - 1);
        // byte offset of the 64 B group row: pixel * 16 ch * 4 B
        s_desc[pt][k * 4 + 0] = make_int2((b0 * GS_W + a0) << 6, __float_as_int(wk * u00));
        s_desc[pt][k * 4 + 1] = make_int2((b0 * GS_W + a1) << 6, __float_as_int(wk * u01));
        s_desc[pt][k * 4 + 2] = make_int2((b1 * GS_W + a0) << 6, __float_as_int(wk * u10));
        s_desc[pt][k * 4 + 3] = make_int2((b1 * GS_W + a1) << 6, __float_as_int(wk * u11));
    }
    __syncthreads();

    // ---- Phase 2: lane = (pt-oct, channel); 16 points per wave; inner
    // loop byte-for-byte r3 (4x64B segments/instr, 16-deep load runs).
    {
        int lane = threadIdx.x & 63;
        int wave = threadIdx.x >> 6;   // 0..7
        int ch4  = (lane & 15) << 2;   // byte offset of channel in row
        int ps   = lane >> 4;          // 0..3: point within quartet
        const char* fbc = (const char*)(fg + ((size_t)(n * GS_G + g) << 20));
        #pragma unroll 1
        for (int s = 0; s < 4; ++s) {
            int sl = wave * 16 + s * 4 + ps;
            float acc = 0.0f;
            #pragma unroll
            for (int e = 0; e < 16; ++e) {
                int2 d = s_desc[sl][e];                   // 16-lane broadcast
                float v = *(const float*)(fbc + (size_t)(d.x + ch4));  // 64 B/pt
                acc = fmaf(__int_as_float(d.y), v, acc);
            }
            tile[lane & 15][sl] = acc;                    // <=2-way, free
        }
    }
    __syncthreads();

    // ---- coalesced NCHW write, non-temporal (don't pollute L2 slice)
    int ho  = (p0 >> 8) & 255;
    int wo0 = p0 & 255;                // 0 or 128
    float* ob = out + (size_t)n * GS_IMG + ((size_t)(g * GS_GC) << 16)
              + (size_t)ho * GS_W + wo0;
    int w  = threadIdx.x & 127;
    int c0 = threadIdx.x >> 7;         // 0..3
    #pragma unroll
    for (int c = c0; c < GS_GC; c += 4)
        __builtin_nontemporal_store(tile[c][w], ob + ((size_t)c << 16) + w);
}

extern "C" void kernel_launch(void* const* d_in, const int* in_sizes, int n_in,
                              void* d_out, int out_size, void* d_ws, size_t ws_size,
                              hipStream_t stream) {
    const float* feature = (const float*)d_in[0];
    const float* grid    = (const float*)d_in[1];
    float*       out     = (float*)d_out;
    float*       fg      = (float*)d_ws;           // 128 MiB grouped-NHWC16

    transpose_nchw_to_g16<<<dim3(GS_N * GS_HW / 256), dim3(256), 0, stream>>>(feature, fg);
    gs_fused<<<dim3(GS_N * GS_HW / GS_PTS, GS_G), dim3(512), 0, stream>>>(fg, grid, out);
}

// Round 8
// 414.518 us; speedup vs baseline: 1.0312x; 1.0091x over previous
//
#include <hip/hip_runtime.h>

// Double bilinear grid_sample (align_corners=False, zeros padding).
// feature: [8,64,256,256] f32 NCHW; grid: [8,256,256,2] f32.
//
// r8: ALGORITHMIC split. The fused kernel (r3, 170 us) paid 16 feature
// gathers + 4 random grid gathers per output point; factorizing into
// first = GS(feat,grid); out = GS(first,grid) pays 4+4 feature gathers
// and ZERO random grid gathers (grid read coalesced in both passes).
// Extra cost: materialize first (128 MB grouped, nt write + read) --
// acceptable at 21% HBM. Inner loop of both passes = r3's proven
// optimum byte-for-byte (r4/r5/r6/r7 all regressed it): 4x64B segments
// per instr, desc broadcast from LDS, 16-deep... now 4-deep chains but
// 4x points/block (256 pts, same 256 VMEM instr/block).
//
// Budget: harness 512 MiB re-poison fill (~80 us, immovable) +
// transpose (<78 us, near roofline) + gs1 + gs2.
//
// K1: transpose NCHW -> grouped NHWC16 [n][4][65536 px][16 ch].
// K2 (gs1): first[n][g][p][c] = sum_k wk(p) * fg[n][g][corner_k(p)][c].
// K3 (gs2): out[n][g*16+c][p]  = sum_k wk(p) * first[n][g][corner_k(p)][c].
// Both: blockIdx.x&7 = n (XCD pin), gridDim.y = 4 groups x-fastest
// -> 4 MB live slice per XCD L2.

#define GS_N 8
#define GS_C 64
#define GS_H 256
#define GS_W 256
#define GS_HW (GS_H * GS_W)
#define GS_IMG (GS_C * GS_HW)
#define GS_G 4                 // channel groups
#define GS_GC 16               // channels per group

typedef float f4v __attribute__((ext_vector_type(4)));

__global__ __launch_bounds__(256) void transpose_nchw_to_g16(
        const float* __restrict__ src, float* __restrict__ dst) {
    int b   = blockIdx.x;               // 2048 blocks: 256 hw x 64 c tile
    int n   = b >> 8;
    int hw0 = (b & 255) << 8;

    // Flat 64 KiB: row c = floats [c*256, c*256+256) as 64 float4 slots;
    // logical slot s of row c lives at phys slot s ^ (c>>3).
    __shared__ float lt[GS_C * 256];

    const float* sp = src + (size_t)n * GS_IMG + hw0;

    int l  = threadIdx.x & 63;
    int wv = threadIdx.x >> 6;

    #pragma unroll
    for (int t = 0; t < 16; ++t) {
        int c = (wv << 4) + t;
        f4v v = __builtin_nontemporal_load(
                    (const f4v*)(sp + ((size_t)c << 16) + (l << 2)));
        int s = l ^ (c >> 3);           // swizzled float4 slot
        *(f4v*)&lt[(c << 8) + (s << 2)] = v;
    }
    __syncthreads();

    int c4  = threadIdx.x & 15;
    int h0  = threadIdx.x >> 4;
    int g   = c4 >> 2;
    int cl0 = (c4 & 3) << 2;
    int swz = c4 >> 1;                  // == (4*c4+k)>>3 for k=0..3
    int c0  = c4 << 2;
    float* dp = dst + ((size_t)(n * GS_G + g) << 20)   // 4 MB slice
              + ((size_t)hw0 << 4) + cl0;
    #pragma unroll
    for (int t = 0; t < 16; ++t) {
        int hh  = h0 + (t << 4);
        int col = (((hh >> 2) ^ swz) << 2) | (hh & 3);  // float idx in row
        f4v v;
        v.x = lt[((c0 + 0) << 8) + col];
        v.y = lt[((c0 + 1) << 8) + col];
        v.z = lt[((c0 + 2) << 8) + col];
        v.w = lt[((c0 + 3) << 8) + col];
        __builtin_nontemporal_store(v, (f4v*)(dp + ((size_t)hh << 4)));
    }
}

__device__ __forceinline__ void corner_setup(float gx, float gy,
        int& x0, int& y0, float& w00, float& w01, float& w10, float& w11) {
    // ix = ((gx+1)*256 - 1)*0.5 = gx*128 + 127.5
    float ix = fmaf(gx, 128.0f, 127.5f);
    float iy = fmaf(gy, 128.0f, 127.5f);
    float fx0 = floorf(ix), fy0 = floorf(iy);
    float fx = ix - fx0, fy = iy - fy0;
    x0 = (int)fx0; y0 = (int)fy0;
    int x1 = x0 + 1, y1 = y0 + 1;
    float mx0 = (x0 >= 0 && x0 < GS_W) ? 1.0f : 0.0f;
    float mx1 = (x1 >= 0 && x1 < GS_W) ? 1.0f : 0.0f;
    float my0 = (y0 >= 0 && y0 < GS_H) ? 1.0f : 0.0f;
    float my1 = (y1 >= 0 && y1 < GS_H) ? 1.0f : 0.0f;
    w00 = (1.0f - fx) * (1.0f - fy) * mx0 * my0;
    w01 = fx * (1.0f - fy) * mx1 * my0;
    w10 = (1.0f - fx) * fy * mx0 * my1;
    w11 = fx * fy * mx1 * my1;
}

// Phase 1 (shared shape): thread = point; 4 descriptors into LDS.
// s_desc[256][4] = 8 KB. Phase-2 read: 4 distinct rows -> banks
// {8sl%32}+2e distinct, 16-lane broadcast each: conflict-free.
__device__ __forceinline__ void build_descs(
        int2 (*s_desc)[4], const float* __restrict__ grid, int n, int p0) {
    int pt = threadIdx.x;
    float2 gp = ((const float2*)grid)[(size_t)n * GS_HW + p0 + pt];
    int x0, y0; float w00, w01, w10, w11;
    corner_setup(gp.x, gp.y, x0, y0, w00, w01, w10, w11);
    int x0c = min(max(x0, 0), GS_W - 1), x1c = min(max(x0 + 1, 0), GS_W - 1);
    int y0c = min(max(y0, 0), GS_H - 1), y1c = min(max(y0 + 1, 0), GS_H - 1);
    // byte offset of the 64 B group row: pixel * 16 ch * 4 B
    s_desc[pt][0] = make_int2((y0c * GS_W + x0c) << 6, __float_as_int(w00));
    s_desc[pt][1] = make_int2((y0c * GS_W + x1c) << 6, __float_as_int(w01));
    s_desc[pt][2] = make_int2((y1c * GS_W + x0c) << 6, __float_as_int(w10));
    s_desc[pt][3] = make_int2((y1c * GS_W + x1c) << 6, __float_as_int(w11));
}

__global__ __launch_bounds__(256) void gs_level1(
        const float* __restrict__ fg, const float* __restrict__ grid,
        float* __restrict__ first) {
    int bx  = blockIdx.x;              // 2048
    int g   = blockIdx.y;              // group, x-fastest dispatch
    int n   = bx & 7;                  // XCD pin (2048 % 8 == 0)
    int p0  = (bx >> 3) << 8;          // 256 points = one output row

    __shared__ int2 s_desc[256][4];

    build_descs(s_desc, grid, n, p0);
    __syncthreads();

    // Phase 2: r3 inner loop; lane = (pt-quartet ps, channel).
    int lane = threadIdx.x & 63;
    int wave = threadIdx.x >> 6;
    int ch4  = (lane & 15) << 2;
    int ps   = lane >> 4;
    const char* fbc = (const char*)(fg + ((size_t)(n * GS_G + g) << 20));
    float* fw = first + ((size_t)(n * GS_G + g) << 20) + (size_t)p0 * GS_GC;
    #pragma unroll 1
    for (int s = 0; s < 16; ++s) {
        int sl = wave * 64 + s * 4 + ps;
        float acc = 0.0f;
        #pragma unroll
        for (int e = 0; e < 4; ++e) {
            int2 d = s_desc[sl][e];                   // 16-lane broadcast
            float v = *(const float*)(fbc + (size_t)(d.x + ch4));  // 64 B/pt
            acc = fmaf(__int_as_float(d.y), v, acc);
        }
        // contiguous 256 B per wave instr; nt keeps L2 for the gathers
        __builtin_nontemporal_store(acc, fw + sl * GS_GC + (lane & 15));
    }
}

__global__ __launch_bounds__(256) void gs_level2(
        const float* __restrict__ first, const float* __restrict__ grid,
        float* __restrict__ out) {
    int bx  = blockIdx.x;              // 2048
    int g   = blockIdx.y;
    int n   = bx & 7;
    int idx = bx >> 3;                 // 0..255 = output row y
    int p0  = idx << 8;

    __shared__ int2  s_desc[256][4];
    __shared__ float tile[GS_GC][257]; // [ch][point]; (ch+pt)%32 ~2-way

    build_descs(s_desc, grid, n, p0);
    __syncthreads();

    int lane = threadIdx.x & 63;
    int wave = threadIdx.x >> 6;
    int ch4  = (lane & 15) << 2;
    int ps   = lane >> 4;
    const char* fbc = (const char*)(first + ((size_t)(n * GS_G + g) << 20));
    #pragma unroll 1
    for (int s = 0; s < 16; ++s) {
        int sl = wave * 64 + s * 4 + ps;
        float acc = 0.0f;
        #pragma unroll
        for (int e = 0; e < 4; ++e) {
            int2 d = s_desc[sl][e];                   // 16-lane broadcast
            float v = *(const float*)(fbc + (size_t)(d.x + ch4));  // 64 B/pt
            acc = fmaf(__int_as_float(d.y), v, acc);
        }
        tile[lane & 15][sl] = acc;
    }
    __syncthreads();

    // coalesced NCHW write: full 256-px row per channel, nt
    float* ob = out + (size_t)n * GS_IMG + ((size_t)(g * GS_GC) << 16)
              + ((size_t)idx << 8);
    #pragma unroll
    for (int c = 0; c < GS_GC; ++c)
        __builtin_nontemporal_store(tile[c][threadIdx.x],
                                    ob + ((size_t)c << 16) + threadIdx.x);
}

extern "C" void kernel_launch(void* const* d_in, const int* in_sizes, int n_in,
                              void* d_out, int out_size, void* d_ws, size_t ws_size,
                              hipStream_t stream) {
    const float* feature = (const float*)d_in[0];
    const float* grid    = (const float*)d_in[1];
    float*       out     = (float*)d_out;
    float*       fg      = (float*)d_ws;                    // 128 MiB grouped feat
    float*       first   = (float*)d_ws + ((size_t)1 << 25); // +128 MiB grouped first

    transpose_nchw_to_g16<<<dim3(GS_N * GS_HW / 256), dim3(256), 0, stream>>>(feature, fg);
    gs_level1<<<dim3(GS_N * GS_HW / 256, GS_G), dim3(256), 0, stream>>>(fg, grid, first);
    gs_level2<<<dim3(GS_N * GS_HW / 256, GS_G), dim3(256), 0, stream>>>(first, grid, out);
}

// Round 9
// 411.493 us; speedup vs baseline: 1.0388x; 1.0074x over previous
//
#include <hip/hip_runtime.h>

// Double bilinear grid_sample (align_corners=False, zeros padding).
// feature: [8,64,256,256] f32 NCHW; grid: [8,256,256,2] f32.
//
// r8: ALGORITHMIC split: first = GS(feat,grid); out = GS(first,grid) ->
// 4+4 feature gathers/pt (r3-fused: 16) and zero random grid gathers.
// FETCH dropped to 97 MB/pass (near-compulsory) but dur REGRESSED
// (116+~115 vs 170): #pragma unroll 1 made each s-iter a 4-deep
// dependent bundle -> per-wave MLP fell 16 -> 4, VALUBusy 57 -> 15%.
// r9: unroll s-loop by 4 (iterations fully independent: own acc, own
// point) so the scheduler hoists 16 loads ahead of the fma/store tail,
// restoring r3's proven 16-deep load runs at HALF the load count.
// Per-point e-order unchanged -> bit-identical output.
//
// Budget: harness 512 MiB re-poison fill (~80 us, immovable) +
// transpose (<78 us, near roofline) + gs1 + gs2.
//
// K1: transpose NCHW -> grouped NHWC16 [n][4][65536 px][16 ch].
// K2 (gs1): first[n][g][p][c] = sum_k wk(p) * fg[n][g][corner_k(p)][c].
// K3 (gs2): out[n][g*16+c][p]  = sum_k wk(p) * first[n][g][corner_k(p)][c].
// Both: blockIdx.x&7 = n (XCD pin), gridDim.y = 4 groups x-fastest
// -> 4 MB live slice per XCD L2.

#define GS_N 8
#define GS_C 64
#define GS_H 256
#define GS_W 256
#define GS_HW (GS_H * GS_W)
#define GS_IMG (GS_C * GS_HW)
#define GS_G 4                 // channel groups
#define GS_GC 16               // channels per group

typedef float f4v __attribute__((ext_vector_type(4)));

__global__ __launch_bounds__(256) void transpose_nchw_to_g16(
        const float* __restrict__ src, float* __restrict__ dst) {
    int b   = blockIdx.x;               // 2048 blocks: 256 hw x 64 c tile
    int n   = b >> 8;
    int hw0 = (b & 255) << 8;

    // Flat 64 KiB: row c = floats [c*256, c*256+256) as 64 float4 slots;
    // logical slot s of row c lives at phys slot s ^ (c>>3).
    __shared__ float lt[GS_C * 256];

    const float* sp = src + (size_t)n * GS_IMG + hw0;

    int l  = threadIdx.x & 63;
    int wv = threadIdx.x >> 6;

    #pragma unroll
    for (int t = 0; t < 16; ++t) {
        int c = (wv << 4) + t;
        f4v v = __builtin_nontemporal_load(
                    (const f4v*)(sp + ((size_t)c << 16) + (l << 2)));
        int s = l ^ (c >> 3);           // swizzled float4 slot
        *(f4v*)&lt[(c << 8) + (s << 2)] = v;
    }
    __syncthreads();

    int c4  = threadIdx.x & 15;
    int h0  = threadIdx.x >> 4;
    int g   = c4 >> 2;
    int cl0 = (c4 & 3) << 2;
    int swz = c4 >> 1;                  // == (4*c4+k)>>3 for k=0..3
    int c0  = c4 << 2;
    float* dp = dst + ((size_t)(n * GS_G + g) << 20)   // 4 MB slice
              + ((size_t)hw0 << 4) + cl0;
    #pragma unroll
    for (int t = 0; t < 16; ++t) {
        int hh  = h0 + (t << 4);
        int col = (((hh >> 2) ^ swz) << 2) | (hh & 3);  // float idx in row
        f4v v;
        v.x = lt[((c0 + 0) << 8) + col];
        v.y = lt[((c0 + 1) << 8) + col];
        v.z = lt[((c0 + 2) << 8) + col];
        v.w = lt[((c0 + 3) << 8) + col];
        __builtin_nontemporal_store(v, (f4v*)(dp + ((size_t)hh << 4)));
    }
}

__device__ __forceinline__ void corner_setup(float gx, float gy,
        int& x0, int& y0, float& w00, float& w01, float& w10, float& w11) {
    // ix = ((gx+1)*256 - 1)*0.5 = gx*128 + 127.5
    float ix = fmaf(gx, 128.0f, 127.5f);
    float iy = fmaf(gy, 128.0f, 127.5f);
    float fx0 = floorf(ix), fy0 = floorf(iy);
    float fx = ix - fx0, fy = iy - fy0;
    x0 = (int)fx0; y0 = (int)fy0;
    int x1 = x0 + 1, y1 = y0 + 1;
    float mx0 = (x0 >= 0 && x0 < GS_W) ? 1.0f : 0.0f;
    float mx1 = (x1 >= 0 && x1 < GS_W) ? 1.0f : 0.0f;
    float my0 = (y0 >= 0 && y0 < GS_H) ? 1.0f : 0.0f;
    float my1 = (y1 >= 0 && y1 < GS_H) ? 1.0f : 0.0f;
    w00 = (1.0f - fx) * (1.0f - fy) * mx0 * my0;
    w01 = fx * (1.0f - fy) * mx1 * my0;
    w10 = (1.0f - fx) * fy * mx0 * my1;
    w11 = fx * fy * mx1 * my1;
}

// Phase 1 (shared shape): thread = point; 4 descriptors into LDS.
__device__ __forceinline__ void build_descs(
        int2 (*s_desc)[4], const float* __restrict__ grid, int n, int p0) {
    int pt = threadIdx.x;
    float2 gp = ((const float2*)grid)[(size_t)n * GS_HW + p0 + pt];
    int x0, y0; float w00, w01, w10, w11;
    corner_setup(gp.x, gp.y, x0, y0, w00, w01, w10, w11);
    int x0c = min(max(x0, 0), GS_W - 1), x1c = min(max(x0 + 1, 0), GS_W - 1);
    int y0c = min(max(y0, 0), GS_H - 1), y1c = min(max(y0 + 1, 0), GS_H - 1);
    // byte offset of the 64 B group row: pixel * 16 ch * 4 B
    s_desc[pt][0] = make_int2((y0c * GS_W + x0c) << 6, __float_as_int(w00));
    s_desc[pt][1] = make_int2((y0c * GS_W + x1c) << 6, __float_as_int(w01));
    s_desc[pt][2] = make_int2((y1c * GS_W + x0c) << 6, __float_as_int(w10));
    s_desc[pt][3] = make_int2((y1c * GS_W + x1c) << 6, __float_as_int(w11));
}

__global__ __launch_bounds__(256) void gs_level1(
        const float* __restrict__ fg, const float* __restrict__ grid,
        float* __restrict__ first) {
    int bx  = blockIdx.x;              // 2048
    int g   = blockIdx.y;              // group, x-fastest dispatch
    int n   = bx & 7;                  // XCD pin (2048 % 8 == 0)
    int p0  = (bx >> 3) << 8;          // 256 points = one output row

    __shared__ int2 s_desc[256][4];

    build_descs(s_desc, grid, n, p0);
    __syncthreads();

    // Phase 2: lane = (pt-quartet ps, channel). unroll 4: the 4
    // s-iterations are independent (own acc/point) -> 16 loads in
    // flight, r3's proven MLP at half the load count.
    int lane = threadIdx.x & 63;
    int wave = threadIdx.x >> 6;
    int ch4  = (lane & 15) << 2;
    int ps   = lane >> 4;
    const char* fbc = (const char*)(fg + ((size_t)(n * GS_G + g) << 20));
    float* fw = first + ((size_t)(n * GS_G + g) << 20) + (size_t)p0 * GS_GC;
    #pragma unroll 4
    for (int s = 0; s < 16; ++s) {
        int sl = wave * 64 + s * 4 + ps;
        float acc = 0.0f;
        #pragma unroll
        for (int e = 0; e < 4; ++e) {
            int2 d = s_desc[sl][e];                   // 16-lane broadcast
            float v = *(const float*)(fbc + (size_t)(d.x + ch4));  // 64 B/pt
            acc = fmaf(__int_as_float(d.y), v, acc);
        }
        // contiguous 256 B per wave instr; nt keeps L2 for the gathers
        __builtin_nontemporal_store(acc, fw + sl * GS_GC + (lane & 15));
    }
}

__global__ __launch_bounds__(256) void gs_level2(
        const float* __restrict__ first, const float* __restrict__ grid,
        float* __restrict__ out) {
    int bx  = blockIdx.x;              // 2048
    int g   = blockIdx.y;
    int n   = bx & 7;
    int idx = bx >> 3;                 // 0..255 = output row y
    int p0  = idx << 8;

    __shared__ int2  s_desc[256][4];
    __shared__ float tile[GS_GC][257]; // [ch][point]; (ch+pt)%32 ~2-way

    build_descs(s_desc, grid, n, p0);
    __syncthreads();

    int lane = threadIdx.x & 63;
    int wave = threadIdx.x >> 6;
    int ch4  = (lane & 15) << 2;
    int ps   = lane >> 4;
    const char* fbc = (const char*)(first + ((size_t)(n * GS_G + g) << 20));
    #pragma unroll 4
    for (int s = 0; s < 16; ++s) {
        int sl = wave * 64 + s * 4 + ps;
        float acc = 0.0f;
        #pragma unroll
        for (int e = 0; e < 4; ++e) {
            int2 d = s_desc[sl][e];                   // 16-lane broadcast
            float v = *(const float*)(fbc + (size_t)(d.x + ch4));  // 64 B/pt
            acc = fmaf(__int_as_float(d.y), v, acc);
        }
        tile[lane & 15][sl] = acc;
    }
    __syncthreads();

    // coalesced NCHW write: full 256-px row per channel, nt
    float* ob = out + (size_t)n * GS_IMG + ((size_t)(g * GS_GC) << 16)
              + ((size_t)idx << 8);
    #pragma unroll
    for (int c = 0; c < GS_GC; ++c)
        __builtin_nontemporal_store(tile[c][threadIdx.x],
                                    ob + ((size_t)c << 16) + threadIdx.x);
}

extern "C" void kernel_launch(void* const* d_in, const int* in_sizes, int n_in,
                              void* d_out, int out_size, void* d_ws, size_t ws_size,
                              hipStream_t stream) {
    const float* feature = (const float*)d_in[0];
    const float* grid    = (const float*)d_in[1];
    float*       out     = (float*)d_out;
    float*       fg      = (float*)d_ws;                    // 128 MiB grouped feat
    float*       first   = (float*)d_ws + ((size_t)1 << 25); // +128 MiB grouped first

    transpose_nchw_to_g16<<<dim3(GS_N * GS_HW / 256), dim3(256), 0, stream>>>(feature, fg);
    gs_level1<<<dim3(GS_N * GS_HW / 256, GS_G), dim3(256), 0, stream>>>(fg, grid, first);
    gs_level2<<<dim3(GS_N * GS_HW / 256, GS_G), dim3(256), 0, stream>>>(first, grid, out);
}